// Round 19
// baseline (671.494 us; speedup 1.0000x reference)
//
#include <hip/hip_runtime.h>
#include <math.h>

// ---------------------------------------------------------------------------
// Coherent DONN: 3 x (phase mask -> ifft2(fft2(f)*H)) -> |f|^2 -> FC(10)
// R26: R22's fp16-LDS k_col minus 16 VGPR (hy table moved to LDS) to test
// the phase-diversity hypothesis CLEANLY. R22: LDS 34.9 KB (4 blocks fit
// by LDS) but VGPR 100 capped residency at 2 blocks/CU (3 blocks needs
// <=85/wave: 6 waves/SIMD x 85 = 510 <= 512) -> its null result never
// tested diversity. hyl reads are stride-8B (2-way bank alias = free,
// R7 evidence). Same 16-col tiles / staging / FETCH pattern as R20.
//   If VGPR <= 85: 3 barrier groups/CU -> VALU/LDS phases of different
//   blocks overlap -> k_col 117 -> ~100-108. If VGPR > 85: flat (null),
//   and 652 us is this structure's floor.
// Everything else = R20/R25 verified best (651.8 us): persistent+prefetch
// rows+k_col, launch-per-block k_rlast, soft LDS fences (R17 HW-verified),
// separable hx/hy with 1/512+1/512 scale split (R22), pair-column FFT.
// Field stored fp16 complex (half2v, 4 B/elem); compute fp32.
// FFT: 512-pt Stockham radix-8, 64 threads (1 wave) per FFT, 3 stages.
// ---------------------------------------------------------------------------

#define PAD(i) ((i) + ((i) >> 4))      // LDS padding: breaks 16-element strides
#define LSTR 545                        // row-kernel LDS stride (float2 elems)
#define PSTR 545                        // k_col per-pair stride (half4 elems)

typedef __attribute__((ext_vector_type(2))) _Float16 half2v;  // 4 B field elem
typedef __attribute__((ext_vector_type(4))) _Float16 half4v;  // 8 B pair elem
typedef __attribute__((ext_vector_type(8))) _Float16 half8;   // 16 B = 4 elems

// Compiler-only ordering for same-wave LDS exchange (emits no instruction;
// same-wave DS ops are processed in issue order by HW — verified R17).
__device__ __forceinline__ void wave_lds_order() {
  asm volatile("" ::: "memory");
}

__device__ __forceinline__ float2 cadd(float2 a, float2 b){ return make_float2(a.x+b.x, a.y+b.y); }
__device__ __forceinline__ float2 csub(float2 a, float2 b){ return make_float2(a.x-b.x, a.y-b.y); }
__device__ __forceinline__ float2 cmul(float2 a, float2 b){ return make_float2(a.x*b.x - a.y*b.y, a.x*b.y + a.y*b.x); }

// S=-1: a*b ; S=+1: a*conj(b)  (tw tables hold FORWARD twiddles e^{-i...})
template<int S>
__device__ __forceinline__ float2 cmul_s(float2 a, float2 b) {
  return (S < 0) ? make_float2(a.x*b.x - a.y*b.y, a.x*b.y + a.y*b.x)
                 : make_float2(a.x*b.x + a.y*b.y, a.y*b.x - a.x*b.y);
}

template<int S>  // multiply by S*i  (S=-1 forward, S=+1 inverse)
__device__ __forceinline__ float2 crot(float2 z){
  return (S > 0) ? make_float2(-z.y, z.x) : make_float2(z.y, -z.x);
}

// natural-order DFT-8: V[k] = sum_n v[n] e^{S*2pi*i*nk/8}
template<int S>
__device__ __forceinline__ void fft8(float2 v[8]) {
  const float sq = 0.70710678118654752440f;
  float2 t0 = cadd(v[0], v[4]), t1 = csub(v[0], v[4]);
  float2 t2 = cadd(v[2], v[6]), t3 = csub(v[2], v[6]);
  float2 E0 = cadd(t0, t2), E2 = csub(t0, t2);
  float2 rt3 = crot<S>(t3);
  float2 E1 = cadd(t1, rt3), E3 = csub(t1, rt3);
  float2 u0 = cadd(v[1], v[5]), u1 = csub(v[1], v[5]);
  float2 u2 = cadd(v[3], v[7]), u3 = csub(v[3], v[7]);
  float2 O0 = cadd(u0, u2), O2 = csub(u0, u2);
  float2 ru3 = crot<S>(u3);
  float2 O1 = cadd(u1, ru3), O3 = csub(u1, ru3);
  float2 O1w = make_float2(sq*(O1.x - (float)S*O1.y), sq*((float)S*O1.x + O1.y));
  float2 O2w = crot<S>(O2);
  float2 O3w = make_float2(-sq*(O3.x + (float)S*O3.y), sq*((float)S*O3.x - O3.y));
  v[0] = cadd(E0, O0);  v[4] = csub(E0, O0);
  v[1] = cadd(E1, O1w); v[5] = csub(E1, O1w);
  v[2] = cadd(E2, O2w); v[6] = csub(E2, O2w);
  v[3] = cadd(E3, O3w); v[7] = csub(E3, O3w);
}

// Forward twiddle tables: tw2[r-1]=e^{-2pi*i*r*(t&7)/64}, tw3=.../512
__device__ __forceinline__ void mktw(float2 tw2[7], float2 tw3[7], int t) {
  float a2 = -6.28318530717958647692f * (float)(t & 7) / 64.0f;
  float a3 = -6.28318530717958647692f * (float)(t & 63) / 512.0f;
  float s2, c2; __sincosf(a2, &s2, &c2);
  float s3, c3; __sincosf(a3, &s3, &c3);
  float2 w2 = make_float2(c2, s2), w3 = make_float2(c3, s3);
  tw2[0] = w2; tw3[0] = w3;
  #pragma unroll
  for (int r = 1; r < 7; ++r) { tw2[r] = cmul(tw2[r-1], w2); tw3[r] = cmul(tw3[r-1], w3); }
}

// --- Rows: soft-fenced single-column FFT with tables (fp32 LDS) ---
template<int S>
__device__ __forceinline__ void fft512_w(float2 v[8], float2* __restrict__ B, int t,
                                         const float2 tw2[7], const float2 tw3[7]) {
  fft8<S>(v);
  #pragma unroll
  for (int r = 0; r < 8; ++r) B[PAD(8*t + r)] = v[r];
  wave_lds_order();
  #pragma unroll
  for (int r = 0; r < 8; ++r) v[r] = B[PAD(t + 64*r)];
  #pragma unroll
  for (int r = 1; r < 8; ++r) v[r] = cmul_s<S>(v[r], tw2[r-1]);
  fft8<S>(v);
  int d = ((t >> 3) << 6) | (t & 7);
  #pragma unroll
  for (int r = 0; r < 8; ++r) B[PAD(d + 8*r)] = v[r];
  wave_lds_order();
  #pragma unroll
  for (int r = 0; r < 8; ++r) v[r] = B[PAD(t + 64*r)];
  #pragma unroll
  for (int r = 1; r < 8; ++r) v[r] = cmul_s<S>(v[r], tw3[r-1]);
  fft8<S>(v);
}

// fp16 pack/unpack for the pair exchange
__device__ __forceinline__ half4v pack4(float2 a, float2 b) {
  half4v h; h[0] = (_Float16)a.x; h[1] = (_Float16)a.y;
  h[2] = (_Float16)b.x; h[3] = (_Float16)b.y; return h;
}
__device__ __forceinline__ void unpack4(half4v h, float2& a, float2& b) {
  a = make_float2((float)h[0], (float)h[1]);
  b = make_float2((float)h[2], (float)h[3]);
}

// --- k_col: two columns per wave, fp16 b64 LDS exchanges, shared tables ---
template<int S>
__device__ __forceinline__ void fft512_pair_h(float2 vA[8], float2 vB[8],
                                              half4v* __restrict__ B, int t,
                                              const float2 tw2[7], const float2 tw3[7]) {
  fft8<S>(vA); fft8<S>(vB);
  #pragma unroll
  for (int r = 0; r < 8; ++r) B[PAD(8*t + r)] = pack4(vA[r], vB[r]);
  wave_lds_order();
  #pragma unroll
  for (int r = 0; r < 8; ++r) unpack4(B[PAD(t + 64*r)], vA[r], vB[r]);
  #pragma unroll
  for (int r = 1; r < 8; ++r) {
    vA[r] = cmul_s<S>(vA[r], tw2[r-1]); vB[r] = cmul_s<S>(vB[r], tw2[r-1]);
  }
  fft8<S>(vA); fft8<S>(vB);
  int d = ((t >> 3) << 6) | (t & 7);
  #pragma unroll
  for (int r = 0; r < 8; ++r) B[PAD(d + 8*r)] = pack4(vA[r], vB[r]);
  wave_lds_order();
  #pragma unroll
  for (int r = 0; r < 8; ++r) unpack4(B[PAD(t + 64*r)], vA[r], vB[r]);
  #pragma unroll
  for (int r = 1; r < 8; ++r) {
    vA[r] = cmul_s<S>(vA[r], tw3[r-1]); vB[r] = cmul_s<S>(vB[r], tw3[r-1]);
  }
  fft8<S>(vA); fft8<S>(vB);
}

// fp16 field element helpers
__device__ __forceinline__ float2 h2f(half2v h) { return make_float2((float)h[0], (float)h[1]); }
__device__ __forceinline__ half2v f2h(float2 v) { half2v h; h[0] = (_Float16)v.x; h[1] = (_Float16)v.y; return h; }

// ---------------------------------------------------------------------------

// Separable transfer function tables, fp64 phase (kz ~ 4.1e5 rad).
// hx[u] = e^{-i pi lam z fu^2};  hy[w] = e^{i(kz - pi lam z fw^2)} / 512.
// (1/N^2 split: 1/512 here, 1/512 applied in fp32 regs in k_col.)
__global__ __launch_bounds__(256) void k_hinit(float2* __restrict__ hx,
                                               float2* __restrict__ hy) {
  int idx = blockIdx.x * 256 + threadIdx.x;          // 0..1023
  int u = idx & 511;
  double f = (double)(u < 256 ? u : u - 512) * 1953.125;  // 1/(512*1e-6)
  const double LAM = 5.32e-7, ZD = 0.035;
  const double PI = 3.14159265358979323846;
  double s, c;
  if (idx < 512) {
    double ang = -PI * LAM * ZD * f * f;
    sincos(ang, &s, &c);
    hx[u] = make_float2((float)c, (float)s);
  } else {
    double ang = (2.0 * PI / LAM) * ZD - PI * LAM * ZD * f * f;
    sincos(ang, &s, &c);
    const double sc = 1.0 / 512.0;
    hy[u] = make_float2((float)(c * sc), (float)(s * sc));
  }
}

// R1 (persistent): field = x * e^{i*phi0}; row forward FFT. 4 rows/group.
__global__ __launch_bounds__(256) void k_r1(const float* __restrict__ x,
                                            const float* __restrict__ ph,
                                            half2v* __restrict__ F, int ng) {
  __shared__ float2 lds[4 * LSTR];
  int tid = threadIdx.x;
  int t = tid & 63, rl = tid >> 6;
  float2 tw2[7], tw3[7];
  mktw(tw2, tw3, t);
  int grp = blockIdx.x;
  float pfx[8], pfp[8];
  if (grp < ng) {                         // prologue prefetch
    size_t row = (size_t)grp * 4 + rl;
    const float* xr = x + row * 512;
    const float* pr = ph + (size_t)(row & 511) * 512;
    #pragma unroll
    for (int r = 0; r < 8; ++r) { pfx[r] = xr[t + 64*r]; pfp[r] = pr[t + 64*r]; }
  }
  while (grp < ng) {
    size_t row = (size_t)grp * 4 + rl;
    float2 v[8];
    #pragma unroll
    for (int r = 0; r < 8; ++r) {        // consume prefetch regs
      float sn, cs; __sincosf(pfp[r], &sn, &cs);
      v[r] = make_float2(pfx[r] * cs, pfx[r] * sn);
    }
    int next = grp + (int)gridDim.x;     // issue next group's loads now;
    if (next < ng) {                     // they fly under the FFT
      size_t nrow = (size_t)next * 4 + rl;
      const float* xr = x + nrow * 512;
      const float* pr = ph + (size_t)(nrow & 511) * 512;
      #pragma unroll
      for (int r = 0; r < 8; ++r) { pfx[r] = xr[t + 64*r]; pfp[r] = pr[t + 64*r]; }
    }
    fft512_w<-1>(v, lds + rl * LSTR, t, tw2, tw3);
    half2v* Fr = F + row * 512;
    #pragma unroll
    for (int r = 0; r < 8; ++r) Fr[t + 64*r] = f2h(v[r]);
    grp = next;
  }
}

// R2/R3 (persistent): row iFFT -> * e^{i*phi_l} -> row FFT (in registers).
__global__ __launch_bounds__(256) void k_rmid(half2v* __restrict__ F,
                                              const float* __restrict__ ph, int ng) {
  __shared__ float2 lds[4 * LSTR];
  int tid = threadIdx.x;
  int t = tid & 63, rl = tid >> 6;
  float2 tw2[7], tw3[7];
  mktw(tw2, tw3, t);
  int grp = blockIdx.x;
  half2v pff[8]; float pfp[8];
  if (grp < ng) {                         // prologue prefetch
    size_t row = (size_t)grp * 4 + rl;
    const half2v* Fr = F + row * 512;
    const float* pr = ph + (size_t)(row & 511) * 512;
    #pragma unroll
    for (int r = 0; r < 8; ++r) { pff[r] = Fr[t + 64*r]; pfp[r] = pr[t + 64*r]; }
  }
  while (grp < ng) {
    size_t row = (size_t)grp * 4 + rl;
    float2 v[8]; float cur_p[8];
    #pragma unroll
    for (int r = 0; r < 8; ++r) { v[r] = h2f(pff[r]); cur_p[r] = pfp[r]; }
    int next = grp + (int)gridDim.x;     // issue next group's loads now
    if (next < ng) {
      size_t nrow = (size_t)next * 4 + rl;
      const half2v* Fr = F + nrow * 512;
      const float* pr = ph + (size_t)(nrow & 511) * 512;
      #pragma unroll
      for (int r = 0; r < 8; ++r) { pff[r] = Fr[t + 64*r]; pfp[r] = pr[t + 64*r]; }
    }
    fft512_w<1>(v, lds + rl * LSTR, t, tw2, tw3);  // unscaled inverse (1/N^2 split)
    #pragma unroll
    for (int r = 0; r < 8; ++r) {
      float sn, cs; __sincosf(cur_p[r], &sn, &cs);
      v[r] = cmul(v[r], make_float2(cs, sn));
    }
    fft512_w<-1>(v, lds + rl * LSTR, t, tw2, tw3);
    half2v* Fr = F + row * 512;
    #pragma unroll
    for (int r = 0; r < 8; ++r) Fr[t + 64*r] = f2h(v[r]);
    grp = next;
  }
}

// C (persistent, 16-col tiles): grid-stride; per tile: col FFT -> * hy*hx
// -> col iFFT -> *1/512. 512 threads = 8 waves, wave cl owns column pair
// (2cl,2cl+1) as half4v in LDS (b64 exchanges; 34.9 KB + 4 KB hyl).
// hy table in LDS (-16 VGPR vs R22's regs): if allocator lands <=85,
// 3 blocks/CU become resident (6 waves/SIMD x 85 = 510 <= 512).
__global__ __launch_bounds__(512) void k_col(half2v* __restrict__ F,
                                             const float2* __restrict__ hx,
                                             const float2* __restrict__ hy,
                                             int ntiles) {
  __shared__ half4v lds[8 * PSTR];       // 34,880 B
  __shared__ float2 hyl[512];            // 4 KB: hy table (stride-8B reads)
  int tid = threadIdx.x;
  int t = tid & 63, cl = tid >> 6;       // wave cl -> col pair (2cl, 2cl+1)
  hyl[tid] = hy[tid];                    // 512 threads, one elem each
  float2 tw2[7], tw3[7];
  mktw(tw2, tw3, t);

  int tile = blockIdx.x;
  half8 pf[4];
  if (tile < ntiles) {                   // prologue prefetch
    int b = tile >> 5, x0 = (tile & 31) << 4;
    const half8* Fb8 = (const half8*)(F + (size_t)b * 262144);
    #pragma unroll
    for (int i = 0; i < 4; ++i) {
      int f = tid + 512 * i;             // 0..2047
      int yy = f >> 2, c4 = f & 3;       // row 0..511, half8-within-row 0..3
      pf[i] = Fb8[(size_t)yy * 128 + (x0 >> 2) + c4];
    }
  }
  while (tile < ntiles) {
    int b = tile >> 5, x0 = (tile & 31) << 4;
    half8* Fb8 = (half8*)(F + (size_t)b * 262144);
    float2 hxA = hx[x0 + 2*cl], hxB = hx[x0 + 2*cl + 1];
    #pragma unroll
    for (int i = 0; i < 4; ++i) {        // stage tile k into LDS (raw halves)
      int f = tid + 512 * i;
      int yy = f >> 2, c4 = f & 3;
      half8 d = pf[i];
      int pb = PAD(yy);
      half4v lo, hi;
      #pragma unroll
      for (int k = 0; k < 4; ++k) { lo[k] = d[k]; hi[k] = d[4 + k]; }
      lds[(2*c4)     * PSTR + pb] = lo;
      lds[(2*c4 + 1) * PSTR + pb] = hi;
    }
    int next = tile + (int)gridDim.x;    // issue tile k+1's loads now
    if (next < ntiles) {
      int nb = next >> 5, nx0 = (next & 31) << 4;
      const half8* Nb8 = (const half8*)(F + (size_t)nb * 262144);
      #pragma unroll
      for (int i = 0; i < 4; ++i) {
        int f = tid + 512 * i;
        int yy = f >> 2, c4 = f & 3;
        pf[i] = Nb8[(size_t)yy * 128 + (nx0 >> 2) + c4];
      }
    }
    __syncthreads();                     // staging done (also covers hyl init)
    half4v* B = lds + cl * PSTR;
    float2 vA[8], vB[8];
    #pragma unroll
    for (int r = 0; r < 8; ++r) unpack4(B[PAD(t + 64*r)], vA[r], vB[r]);
    fft512_pair_h<-1>(vA, vB, B, t, tw2, tw3);
    #pragma unroll
    for (int r = 0; r < 8; ++r) {
      float2 hyr = hyl[t + 64*r];
      vA[r] = cmul(cmul(vA[r], hyr), hxA);
      vB[r] = cmul(cmul(vB[r], hyr), hxB);
    }
    fft512_pair_h<1>(vA, vB, B, t, tw2, tw3);
    const float s512 = 1.0f / 512.0f;    // second half of the 1/N^2 split
    #pragma unroll
    for (int r = 0; r < 8; ++r) {
      vA[r].x *= s512; vA[r].y *= s512; vB[r].x *= s512; vB[r].y *= s512;
      B[PAD(t + 64*r)] = pack4(vA[r], vB[r]);
    }
    __syncthreads();                      // before cross-wave tile store
    #pragma unroll
    for (int i = 0; i < 4; ++i) {        // store tile k (full 64-B lines)
      int f = tid + 512 * i;
      int yy = f >> 2, c4 = f & 3;
      int pb = PAD(yy);
      half4v a  = lds[(2*c4)     * PSTR + pb];
      half4v bb = lds[(2*c4 + 1) * PSTR + pb];
      half8 o;
      #pragma unroll
      for (int k = 0; k < 4; ++k) { o[k] = a[k]; o[4 + k] = bb[k]; }
      Fb8[(size_t)yy * 128 + (x0 >> 2) + c4] = o;
    }
    __syncthreads();                      // WAR: LDS reused next iteration
    tile = next;
  }
}

// R4 (launch-per-block, R18 form): row iFFT -> intensity -> dot with 10
// class rows -> partial[g][c][y]. Same-y blocks adjacent -> W hot in L2.
__global__ __launch_bounds__(256) void k_rlast(const half2v* __restrict__ F,
                                               const float* __restrict__ W,
                                               float* __restrict__ partial, int m) {
  __shared__ float2 lds[4 * LSTR];
  int tid = threadIdx.x;
  int t = tid & 63, rl = tid >> 6;
  int nq = (m + 3) >> 2;
  int y = blockIdx.x / nq;               // same-y blocks adjacent -> W hot in L2
  int q = blockIdx.x - y * nq;
  int g = q * 4 + rl;                    // image within chunk
  bool act = (g < m);
  const half2v* Fr = F + ((size_t)g * 262144 + (size_t)y * 512);
  float2 tw2[7], tw3[7];
  mktw(tw2, tw3, t);
  float2 v[8];
  #pragma unroll
  for (int r = 0; r < 8; ++r) {
    half2v h = act ? Fr[t + 64*r] : (half2v)(_Float16)0.0f;
    v[r] = h2f(h);
  }
  fft512_w<1>(v, lds + rl * LSTR, t, tw2, tw3);
  float acc[10];
  #pragma unroll
  for (int c = 0; c < 10; ++c) acc[c] = 0.0f;
  const float* Wy = W + (size_t)y * 512;
  #pragma unroll
  for (int r = 0; r < 8; ++r) {
    int e = t + 64*r;
    float I = v[r].x * v[r].x + v[r].y * v[r].y;
    #pragma unroll
    for (int c = 0; c < 10; ++c) acc[c] += I * Wy[(size_t)c * 262144 + e];
  }
  float mine = 0.0f;
  #pragma unroll
  for (int c = 0; c < 10; ++c) {
    float s = acc[c];
    #pragma unroll
    for (int off = 32; off > 0; off >>= 1) s += __shfl_xor(s, off, 64);
    if (t == c) mine = s;
  }
  if (act && t < 10)
    partial[((size_t)g * 10 + t) * 512 + y] = mine;
}

// FC tail: out[g][c] = fc_b[c] + sum_y partial[g][c][y].  One wave per (g,c).
__global__ __launch_bounds__(64) void k_fc(const float* __restrict__ partial,
                                           const float* __restrict__ fc_b,
                                           float* __restrict__ out, int b0, int m) {
  int bid = blockIdx.x;                  // m*10
  int g = bid / 10, c = bid - g * 10;
  int t = threadIdx.x;
  const float* p = partial + ((size_t)g * 10 + c) * 512;
  float s = 0.0f;
  #pragma unroll
  for (int r = 0; r < 8; ++r) s += p[t + 64*r];
  #pragma unroll
  for (int off = 32; off > 0; off >>= 1) s += __shfl_xor(s, off, 64);
  if (t == 0) out[(size_t)(b0 + g) * 10 + c] = s + fc_b[c];
}

// ---------------------------------------------------------------------------

extern "C" void kernel_launch(void* const* d_in, const int* in_sizes, int n_in,
                              void* d_out, int out_size, void* d_ws, size_t ws_size,
                              hipStream_t stream) {
  const float* x    = (const float*)d_in[0];   // (128,1,512,512)
  const float* ph   = (const float*)d_in[1];   // (3,512,512)
  const float* fc_w = (const float*)d_in[2];   // (10, 262144)
  const float* fc_b = (const float*)d_in[3];   // (10,)
  float* out = (float*)d_out;                  // (128,10)

  const size_t IMG = 262144;                   // 512*512
  const size_t PER_IMG = IMG * sizeof(half2v) + 512 * 10 * sizeof(float);
  float2* hx = (float2*)d_ws;                  // 512 float2
  float2* hy = hx + 512;                       // 512 float2
  size_t avail = (ws_size > IMG * sizeof(float2)) ? ws_size - IMG * sizeof(float2) : 0;
  int M = (int)(avail / PER_IMG);              // images per chunk
  if (M < 1) M = 1;
  if (M > 128) M = 128;                        // single chunk: 9 dispatches total
  half2v* F  = (half2v*)((char*)d_ws + IMG * sizeof(float2));
  float* part = (float*)((char*)F + (size_t)M * IMG * sizeof(half2v));

  hipLaunchKernelGGL(k_hinit, dim3(4), dim3(256), 0, stream, hx, hy);

  for (int b0 = 0; b0 < 128; b0 += M) {
    int m = (128 - b0 < M) ? (128 - b0) : M;
    int ng = m * 128;                          // row groups (4 rows each)
    int rgrid = ng < 2048 ? ng : 2048;         // persistent rows (~8 blk/CU)
    int ntiles = m * 32;                       // 16-col tiles
    int cgrid = ntiles < 768 ? ntiles : 768;   // persistent k_col (up to 3 blk/CU)
    int nq = (m + 3) >> 2;
    hipLaunchKernelGGL(k_r1,    dim3(rgrid), dim3(256), 0, stream, x + (size_t)b0 * IMG, ph, F, ng);
    hipLaunchKernelGGL(k_col,   dim3(cgrid), dim3(512), 0, stream, F, (const float2*)hx, (const float2*)hy, ntiles);
    hipLaunchKernelGGL(k_rmid,  dim3(rgrid), dim3(256), 0, stream, F, ph + IMG, ng);
    hipLaunchKernelGGL(k_col,   dim3(cgrid), dim3(512), 0, stream, F, (const float2*)hx, (const float2*)hy, ntiles);
    hipLaunchKernelGGL(k_rmid,  dim3(rgrid), dim3(256), 0, stream, F, ph + 2 * IMG, ng);
    hipLaunchKernelGGL(k_col,   dim3(cgrid), dim3(512), 0, stream, F, (const float2*)hx, (const float2*)hy, ntiles);
    hipLaunchKernelGGL(k_rlast, dim3(512 * nq), dim3(256), 0, stream, F, fc_w, part, m);
    hipLaunchKernelGGL(k_fc,    dim3(m * 10), dim3(64), 0, stream, part, fc_b, out, b0, m);
  }
}

// Round 20
// 648.907 us; speedup vs baseline: 1.0348x; 1.0348x over previous
//
#include <hip/hip_runtime.h>
#include <math.h>

// ---------------------------------------------------------------------------
// Coherent DONN: 3 x (phase mask -> ifft2(fft2(f)*H)) -> |f|^2 -> FC(10)
// R27 = R20/R25 verbatim (verified session best, 651.8-654.1 us).
// SESSION CONCLUSION — structural floor of this design:
//  k_col ~118 us = VALU(~55us) + LDS(~50us) serialized; HBM hidden by
//  prefetch. Ten experiments confirm no remaining lever:
//  - per-wave trades null: R13 (b128 pair exchange), R17 (soft fences,
//    HW-verified same-wave DS in-order), R22 (fp16 LDS), R26 (hy->LDS:
//    allocator holds VGPR at 100, occupancy pinned at 2 blocks/CU).
//  - occupancy levers dead: R8/R21 (sub-16-col tiles 2x-amplify FETCH:
//    32-B read segments split across XCD L2s), R9/R11 (launch-bounds
//    min-waves arg caps VGPR at ~256/w -> catastrophic spill).
//  - transposed-layout replacement dead: R23/R24 (scattered transposed
//    stores amplify WRITE 1.5-2x; coalescing is per-instruction across
//    lanes, max 16 B/lane/instr, no cross-instruction write combining).
//  Wins kept: persistent+prefetch everywhere streaming (R18: k_col
//  151->119; R19: rows 228->~128), launch-per-block k_rlast with same-y
//  W L2 locality (R20; persistent variant was 270 us), separable hx/hy
//  (R13), fp16 field storage, soft LDS fences.
// Field stored fp16 complex (half2v, 4 B/elem); compute fp32.
// FFT: 512-pt Stockham radix-8, 64 threads (1 wave) per FFT, 3 stages.
// ---------------------------------------------------------------------------

#define PAD(i) ((i) + ((i) >> 4))      // LDS padding: breaks 16-element strides
#define LSTR 545                        // row-kernel LDS stride (float2 elems)
#define PSTR 545                        // k_col per-pair stride (float4 elems)

typedef __attribute__((ext_vector_type(2))) _Float16 half2v;  // 4 B field elem
typedef __attribute__((ext_vector_type(8))) _Float16 half8;   // 16 B = 4 elems

// Compiler-only ordering for same-wave LDS exchange (emits no instruction;
// same-wave DS ops are processed in issue order by HW — verified R17).
__device__ __forceinline__ void wave_lds_order() {
  asm volatile("" ::: "memory");
}

__device__ __forceinline__ float2 cadd(float2 a, float2 b){ return make_float2(a.x+b.x, a.y+b.y); }
__device__ __forceinline__ float2 csub(float2 a, float2 b){ return make_float2(a.x-b.x, a.y-b.y); }
__device__ __forceinline__ float2 cmul(float2 a, float2 b){ return make_float2(a.x*b.x - a.y*b.y, a.x*b.y + a.y*b.x); }

// S=-1: a*b ; S=+1: a*conj(b)  (tw tables hold FORWARD twiddles e^{-i...})
template<int S>
__device__ __forceinline__ float2 cmul_s(float2 a, float2 b) {
  return (S < 0) ? make_float2(a.x*b.x - a.y*b.y, a.x*b.y + a.y*b.x)
                 : make_float2(a.x*b.x + a.y*b.y, a.y*b.x - a.x*b.y);
}

template<int S>  // multiply by S*i  (S=-1 forward, S=+1 inverse)
__device__ __forceinline__ float2 crot(float2 z){
  return (S > 0) ? make_float2(-z.y, z.x) : make_float2(z.y, -z.x);
}

// natural-order DFT-8: V[k] = sum_n v[n] e^{S*2pi*i*nk/8}
template<int S>
__device__ __forceinline__ void fft8(float2 v[8]) {
  const float sq = 0.70710678118654752440f;
  float2 t0 = cadd(v[0], v[4]), t1 = csub(v[0], v[4]);
  float2 t2 = cadd(v[2], v[6]), t3 = csub(v[2], v[6]);
  float2 E0 = cadd(t0, t2), E2 = csub(t0, t2);
  float2 rt3 = crot<S>(t3);
  float2 E1 = cadd(t1, rt3), E3 = csub(t1, rt3);
  float2 u0 = cadd(v[1], v[5]), u1 = csub(v[1], v[5]);
  float2 u2 = cadd(v[3], v[7]), u3 = csub(v[3], v[7]);
  float2 O0 = cadd(u0, u2), O2 = csub(u0, u2);
  float2 ru3 = crot<S>(u3);
  float2 O1 = cadd(u1, ru3), O3 = csub(u1, ru3);
  float2 O1w = make_float2(sq*(O1.x - (float)S*O1.y), sq*((float)S*O1.x + O1.y));
  float2 O2w = crot<S>(O2);
  float2 O3w = make_float2(-sq*(O3.x + (float)S*O3.y), sq*((float)S*O3.x - O3.y));
  v[0] = cadd(E0, O0);  v[4] = csub(E0, O0);
  v[1] = cadd(E1, O1w); v[5] = csub(E1, O1w);
  v[2] = cadd(E2, O2w); v[6] = csub(E2, O2w);
  v[3] = cadd(E3, O3w); v[7] = csub(E3, O3w);
}

// Forward twiddle tables: tw2[r-1]=e^{-2pi*i*r*(t&7)/64}, tw3=.../512
__device__ __forceinline__ void mktw(float2 tw2[7], float2 tw3[7], int t) {
  float a2 = -6.28318530717958647692f * (float)(t & 7) / 64.0f;
  float a3 = -6.28318530717958647692f * (float)(t & 63) / 512.0f;
  float s2, c2; __sincosf(a2, &s2, &c2);
  float s3, c3; __sincosf(a3, &s3, &c3);
  float2 w2 = make_float2(c2, s2), w3 = make_float2(c3, s3);
  tw2[0] = w2; tw3[0] = w3;
  #pragma unroll
  for (int r = 1; r < 7; ++r) { tw2[r] = cmul(tw2[r-1], w2); tw3[r] = cmul(tw3[r-1], w3); }
}

// --- Rows: soft-fenced single-column FFT with tables ---
template<int S>
__device__ __forceinline__ void fft512_w(float2 v[8], float2* __restrict__ B, int t,
                                         const float2 tw2[7], const float2 tw3[7]) {
  fft8<S>(v);
  #pragma unroll
  for (int r = 0; r < 8; ++r) B[PAD(8*t + r)] = v[r];
  wave_lds_order();
  #pragma unroll
  for (int r = 0; r < 8; ++r) v[r] = B[PAD(t + 64*r)];
  #pragma unroll
  for (int r = 1; r < 8; ++r) v[r] = cmul_s<S>(v[r], tw2[r-1]);
  fft8<S>(v);
  int d = ((t >> 3) << 6) | (t & 7);
  #pragma unroll
  for (int r = 0; r < 8; ++r) B[PAD(d + 8*r)] = v[r];
  wave_lds_order();
  #pragma unroll
  for (int r = 0; r < 8; ++r) v[r] = B[PAD(t + 64*r)];
  #pragma unroll
  for (int r = 1; r < 8; ++r) v[r] = cmul_s<S>(v[r], tw3[r-1]);
  fft8<S>(v);
}

// --- k_col: two columns per wave, b128 LDS exchanges, shared tables ---
template<int S>
__device__ __forceinline__ void fft512_pair(float2 vA[8], float2 vB[8],
                                            float4* __restrict__ B, int t,
                                            const float2 tw2[7], const float2 tw3[7]) {
  fft8<S>(vA); fft8<S>(vB);
  #pragma unroll
  for (int r = 0; r < 8; ++r)
    B[PAD(8*t + r)] = make_float4(vA[r].x, vA[r].y, vB[r].x, vB[r].y);
  wave_lds_order();
  #pragma unroll
  for (int r = 0; r < 8; ++r) {
    float4 w = B[PAD(t + 64*r)];
    vA[r] = make_float2(w.x, w.y); vB[r] = make_float2(w.z, w.w);
  }
  #pragma unroll
  for (int r = 1; r < 8; ++r) {
    vA[r] = cmul_s<S>(vA[r], tw2[r-1]); vB[r] = cmul_s<S>(vB[r], tw2[r-1]);
  }
  fft8<S>(vA); fft8<S>(vB);
  int d = ((t >> 3) << 6) | (t & 7);
  #pragma unroll
  for (int r = 0; r < 8; ++r)
    B[PAD(d + 8*r)] = make_float4(vA[r].x, vA[r].y, vB[r].x, vB[r].y);
  wave_lds_order();
  #pragma unroll
  for (int r = 0; r < 8; ++r) {
    float4 w = B[PAD(t + 64*r)];
    vA[r] = make_float2(w.x, w.y); vB[r] = make_float2(w.z, w.w);
  }
  #pragma unroll
  for (int r = 1; r < 8; ++r) {
    vA[r] = cmul_s<S>(vA[r], tw3[r-1]); vB[r] = cmul_s<S>(vB[r], tw3[r-1]);
  }
  fft8<S>(vA); fft8<S>(vB);
}

// fp16 field element helpers
__device__ __forceinline__ float2 h2f(half2v h) { return make_float2((float)h[0], (float)h[1]); }
__device__ __forceinline__ half2v f2h(float2 v) { half2v h; h[0] = (_Float16)v.x; h[1] = (_Float16)v.y; return h; }

// ---------------------------------------------------------------------------

// Separable transfer function tables, fp64 phase (kz ~ 4.1e5 rad).
// hx[u] = e^{-i pi lam z fu^2};  hy[w] = e^{i(kz - pi lam z fw^2)} / N^2.
// H[x][ky] = hx[x] * hy[ky].
__global__ __launch_bounds__(256) void k_hinit(float2* __restrict__ hx,
                                               float2* __restrict__ hy) {
  int idx = blockIdx.x * 256 + threadIdx.x;          // 0..1023
  int u = idx & 511;
  double f = (double)(u < 256 ? u : u - 512) * 1953.125;  // 1/(512*1e-6)
  const double LAM = 5.32e-7, ZD = 0.035;
  const double PI = 3.14159265358979323846;
  double s, c;
  if (idx < 512) {
    double ang = -PI * LAM * ZD * f * f;
    sincos(ang, &s, &c);
    hx[u] = make_float2((float)c, (float)s);
  } else {
    double ang = (2.0 * PI / LAM) * ZD - PI * LAM * ZD * f * f;
    sincos(ang, &s, &c);
    const double sc = 1.0 / 262144.0;
    hy[u] = make_float2((float)(c * sc), (float)(s * sc));
  }
}

// R1 (persistent): field = x * e^{i*phi0}; row forward FFT. 4 rows/group.
__global__ __launch_bounds__(256) void k_r1(const float* __restrict__ x,
                                            const float* __restrict__ ph,
                                            half2v* __restrict__ F, int ng) {
  __shared__ float2 lds[4 * LSTR];
  int tid = threadIdx.x;
  int t = tid & 63, rl = tid >> 6;
  float2 tw2[7], tw3[7];
  mktw(tw2, tw3, t);
  int grp = blockIdx.x;
  float pfx[8], pfp[8];
  if (grp < ng) {                         // prologue prefetch
    size_t row = (size_t)grp * 4 + rl;
    const float* xr = x + row * 512;
    const float* pr = ph + (size_t)(row & 511) * 512;
    #pragma unroll
    for (int r = 0; r < 8; ++r) { pfx[r] = xr[t + 64*r]; pfp[r] = pr[t + 64*r]; }
  }
  while (grp < ng) {
    size_t row = (size_t)grp * 4 + rl;
    float2 v[8];
    #pragma unroll
    for (int r = 0; r < 8; ++r) {        // consume prefetch regs
      float sn, cs; __sincosf(pfp[r], &sn, &cs);
      v[r] = make_float2(pfx[r] * cs, pfx[r] * sn);
    }
    int next = grp + (int)gridDim.x;     // issue next group's loads now;
    if (next < ng) {                     // they fly under the FFT
      size_t nrow = (size_t)next * 4 + rl;
      const float* xr = x + nrow * 512;
      const float* pr = ph + (size_t)(nrow & 511) * 512;
      #pragma unroll
      for (int r = 0; r < 8; ++r) { pfx[r] = xr[t + 64*r]; pfp[r] = pr[t + 64*r]; }
    }
    fft512_w<-1>(v, lds + rl * LSTR, t, tw2, tw3);
    half2v* Fr = F + row * 512;
    #pragma unroll
    for (int r = 0; r < 8; ++r) Fr[t + 64*r] = f2h(v[r]);
    grp = next;
  }
}

// R2/R3 (persistent): row iFFT -> * e^{i*phi_l} -> row FFT (in registers).
__global__ __launch_bounds__(256) void k_rmid(half2v* __restrict__ F,
                                              const float* __restrict__ ph, int ng) {
  __shared__ float2 lds[4 * LSTR];
  int tid = threadIdx.x;
  int t = tid & 63, rl = tid >> 6;
  float2 tw2[7], tw3[7];
  mktw(tw2, tw3, t);
  int grp = blockIdx.x;
  half2v pff[8]; float pfp[8];
  if (grp < ng) {                         // prologue prefetch
    size_t row = (size_t)grp * 4 + rl;
    const half2v* Fr = F + row * 512;
    const float* pr = ph + (size_t)(row & 511) * 512;
    #pragma unroll
    for (int r = 0; r < 8; ++r) { pff[r] = Fr[t + 64*r]; pfp[r] = pr[t + 64*r]; }
  }
  while (grp < ng) {
    size_t row = (size_t)grp * 4 + rl;
    float2 v[8]; float cur_p[8];
    #pragma unroll
    for (int r = 0; r < 8; ++r) { v[r] = h2f(pff[r]); cur_p[r] = pfp[r]; }
    int next = grp + (int)gridDim.x;     // issue next group's loads now
    if (next < ng) {
      size_t nrow = (size_t)next * 4 + rl;
      const half2v* Fr = F + nrow * 512;
      const float* pr = ph + (size_t)(nrow & 511) * 512;
      #pragma unroll
      for (int r = 0; r < 8; ++r) { pff[r] = Fr[t + 64*r]; pfp[r] = pr[t + 64*r]; }
    }
    fft512_w<1>(v, lds + rl * LSTR, t, tw2, tw3);  // unscaled inverse (1/N^2 in hy)
    #pragma unroll
    for (int r = 0; r < 8; ++r) {
      float sn, cs; __sincosf(cur_p[r], &sn, &cs);
      v[r] = cmul(v[r], make_float2(cs, sn));
    }
    fft512_w<-1>(v, lds + rl * LSTR, t, tw2, tw3);
    half2v* Fr = F + row * 512;
    #pragma unroll
    for (int r = 0; r < 8; ++r) Fr[t + 64*r] = f2h(v[r]);
    grp = next;
  }
}

// C (persistent): grid-stride over 16-col tiles; per tile: col FFT ->
// * hy*hx -> col iFFT. 512 threads = 8 waves, wave cl owns columns
// (2cl, 2cl+1) interleaved as float4 in LDS. Tile k+1's loads issue right
// after tile k's staging and fly under the FFT chain. (R18: 151->119 us.)
__global__ __launch_bounds__(512) void k_col(half2v* __restrict__ F,
                                             const float2* __restrict__ hx,
                                             const float2* __restrict__ hy,
                                             int ntiles) {
  __shared__ float4 lds[8 * PSTR];       // 69,760 B -> 2 blocks/CU
  int tid = threadIdx.x;
  int t = tid & 63, cl = tid >> 6;       // wave cl -> col pair (2cl, 2cl+1)
  float2 hyv[8];
  #pragma unroll
  for (int r = 0; r < 8; ++r) hyv[r] = hy[t + 64*r];
  float2 tw2[7], tw3[7];
  mktw(tw2, tw3, t);

  int tile = blockIdx.x;
  half8 pf[4];
  if (tile < ntiles) {                   // prologue prefetch
    int b = tile >> 5, x0 = (tile & 31) << 4;
    const half8* Fb8 = (const half8*)(F + (size_t)b * 262144);
    #pragma unroll
    for (int i = 0; i < 4; ++i) {
      int f = tid + 512 * i;
      int yy = f >> 2, c4 = f & 3;
      pf[i] = Fb8[(size_t)yy * 128 + (x0 >> 2) + c4];
    }
  }
  while (tile < ntiles) {
    int b = tile >> 5, x0 = (tile & 31) << 4;
    half8* Fb8 = (half8*)(F + (size_t)b * 262144);
    float2 hxA = hx[x0 + 2*cl], hxB = hx[x0 + 2*cl + 1];
    #pragma unroll
    for (int i = 0; i < 4; ++i) {        // stage tile k into LDS
      int f = tid + 512 * i;
      int yy = f >> 2, c4 = f & 3;
      half8 d = pf[i];
      int pb = PAD(yy);
      lds[(2*c4)     * PSTR + pb] = make_float4((float)d[0], (float)d[1],
                                                (float)d[2], (float)d[3]);
      lds[(2*c4 + 1) * PSTR + pb] = make_float4((float)d[4], (float)d[5],
                                                (float)d[6], (float)d[7]);
    }
    int next = tile + (int)gridDim.x;    // issue tile k+1's loads now
    if (next < ntiles) {
      int nb = next >> 5, nx0 = (next & 31) << 4;
      const half8* Nb8 = (const half8*)(F + (size_t)nb * 262144);
      #pragma unroll
      for (int i = 0; i < 4; ++i) {
        int f = tid + 512 * i;
        int yy = f >> 2, c4 = f & 3;
        pf[i] = Nb8[(size_t)yy * 128 + (nx0 >> 2) + c4];
      }
    }
    __syncthreads();
    float4* B = lds + cl * PSTR;
    float2 vA[8], vB[8];
    #pragma unroll
    for (int r = 0; r < 8; ++r) {
      float4 w = B[PAD(t + 64*r)];
      vA[r] = make_float2(w.x, w.y); vB[r] = make_float2(w.z, w.w);
    }
    fft512_pair<-1>(vA, vB, B, t, tw2, tw3);
    #pragma unroll
    for (int r = 0; r < 8; ++r) {
      vA[r] = cmul(cmul(vA[r], hyv[r]), hxA);
      vB[r] = cmul(cmul(vB[r], hyv[r]), hxB);
    }
    fft512_pair<1>(vA, vB, B, t, tw2, tw3);
    #pragma unroll
    for (int r = 0; r < 8; ++r)
      B[PAD(t + 64*r)] = make_float4(vA[r].x, vA[r].y, vB[r].x, vB[r].y);
    __syncthreads();                      // before cross-wave tile store
    #pragma unroll
    for (int i = 0; i < 4; ++i) {        // store tile k (full 64-B lines)
      int f = tid + 512 * i;
      int yy = f >> 2, c4 = f & 3;
      int pb = PAD(yy);
      float4 a  = lds[(2*c4)     * PSTR + pb];
      float4 bb = lds[(2*c4 + 1) * PSTR + pb];
      half8 o;
      o[0] = (_Float16)a.x;  o[1] = (_Float16)a.y;
      o[2] = (_Float16)a.z;  o[3] = (_Float16)a.w;
      o[4] = (_Float16)bb.x; o[5] = (_Float16)bb.y;
      o[6] = (_Float16)bb.z; o[7] = (_Float16)bb.w;
      Fb8[(size_t)yy * 128 + (x0 >> 2) + c4] = o;
    }
    __syncthreads();                      // WAR: LDS reused next iteration
    tile = next;
  }
}

// R4 (launch-per-block, R18 form): row iFFT -> intensity -> dot with 10
// class rows -> partial[g][c][y]. Same-y blocks adjacent -> W hot in L2.
__global__ __launch_bounds__(256) void k_rlast(const half2v* __restrict__ F,
                                               const float* __restrict__ W,
                                               float* __restrict__ partial, int m) {
  __shared__ float2 lds[4 * LSTR];
  int tid = threadIdx.x;
  int t = tid & 63, rl = tid >> 6;
  int nq = (m + 3) >> 2;
  int y = blockIdx.x / nq;               // same-y blocks adjacent -> W hot in L2
  int q = blockIdx.x - y * nq;
  int g = q * 4 + rl;                    // image within chunk
  bool act = (g < m);
  const half2v* Fr = F + ((size_t)g * 262144 + (size_t)y * 512);
  float2 tw2[7], tw3[7];
  mktw(tw2, tw3, t);
  float2 v[8];
  #pragma unroll
  for (int r = 0; r < 8; ++r) {
    half2v h = act ? Fr[t + 64*r] : (half2v)(_Float16)0.0f;
    v[r] = h2f(h);
  }
  fft512_w<1>(v, lds + rl * LSTR, t, tw2, tw3);
  float acc[10];
  #pragma unroll
  for (int c = 0; c < 10; ++c) acc[c] = 0.0f;
  const float* Wy = W + (size_t)y * 512;
  #pragma unroll
  for (int r = 0; r < 8; ++r) {
    int e = t + 64*r;
    float I = v[r].x * v[r].x + v[r].y * v[r].y;
    #pragma unroll
    for (int c = 0; c < 10; ++c) acc[c] += I * Wy[(size_t)c * 262144 + e];
  }
  float mine = 0.0f;
  #pragma unroll
  for (int c = 0; c < 10; ++c) {
    float s = acc[c];
    #pragma unroll
    for (int off = 32; off > 0; off >>= 1) s += __shfl_xor(s, off, 64);
    if (t == c) mine = s;
  }
  if (act && t < 10)
    partial[((size_t)g * 10 + t) * 512 + y] = mine;
}

// FC tail: out[g][c] = fc_b[c] + sum_y partial[g][c][y].  One wave per (g,c).
__global__ __launch_bounds__(64) void k_fc(const float* __restrict__ partial,
                                           const float* __restrict__ fc_b,
                                           float* __restrict__ out, int b0, int m) {
  int bid = blockIdx.x;                  // m*10
  int g = bid / 10, c = bid - g * 10;
  int t = threadIdx.x;
  const float* p = partial + ((size_t)g * 10 + c) * 512;
  float s = 0.0f;
  #pragma unroll
  for (int r = 0; r < 8; ++r) s += p[t + 64*r];
  #pragma unroll
  for (int off = 32; off > 0; off >>= 1) s += __shfl_xor(s, off, 64);
  if (t == 0) out[(size_t)(b0 + g) * 10 + c] = s + fc_b[c];
}

// ---------------------------------------------------------------------------

extern "C" void kernel_launch(void* const* d_in, const int* in_sizes, int n_in,
                              void* d_out, int out_size, void* d_ws, size_t ws_size,
                              hipStream_t stream) {
  const float* x    = (const float*)d_in[0];   // (128,1,512,512)
  const float* ph   = (const float*)d_in[1];   // (3,512,512)
  const float* fc_w = (const float*)d_in[2];   // (10, 262144)
  const float* fc_b = (const float*)d_in[3];   // (10,)
  float* out = (float*)d_out;                  // (128,10)

  const size_t IMG = 262144;                   // 512*512
  const size_t PER_IMG = IMG * sizeof(half2v) + 512 * 10 * sizeof(float);
  float2* hx = (float2*)d_ws;                  // 512 float2
  float2* hy = hx + 512;                       // 512 float2
  size_t avail = (ws_size > IMG * sizeof(float2)) ? ws_size - IMG * sizeof(float2) : 0;
  int M = (int)(avail / PER_IMG);              // images per chunk
  if (M < 1) M = 1;
  if (M > 128) M = 128;                        // single chunk: 9 dispatches total
  half2v* F  = (half2v*)((char*)d_ws + IMG * sizeof(float2));
  float* part = (float*)((char*)F + (size_t)M * IMG * sizeof(half2v));

  hipLaunchKernelGGL(k_hinit, dim3(4), dim3(256), 0, stream, hx, hy);

  for (int b0 = 0; b0 < 128; b0 += M) {
    int m = (128 - b0 < M) ? (128 - b0) : M;
    int ng = m * 128;                          // row groups (4 rows each)
    int rgrid = ng < 2048 ? ng : 2048;         // persistent rows (~8 blk/CU)
    int ntiles = m * 32;                       // 16-col tiles
    int cgrid = ntiles < 512 ? ntiles : 512;   // persistent k_col (2 blk/CU)
    int nq = (m + 3) >> 2;
    hipLaunchKernelGGL(k_r1,    dim3(rgrid), dim3(256), 0, stream, x + (size_t)b0 * IMG, ph, F, ng);
    hipLaunchKernelGGL(k_col,   dim3(cgrid), dim3(512), 0, stream, F, (const float2*)hx, (const float2*)hy, ntiles);
    hipLaunchKernelGGL(k_rmid,  dim3(rgrid), dim3(256), 0, stream, F, ph + IMG, ng);
    hipLaunchKernelGGL(k_col,   dim3(cgrid), dim3(512), 0, stream, F, (const float2*)hx, (const float2*)hy, ntiles);
    hipLaunchKernelGGL(k_rmid,  dim3(rgrid), dim3(256), 0, stream, F, ph + 2 * IMG, ng);
    hipLaunchKernelGGL(k_col,   dim3(cgrid), dim3(512), 0, stream, F, (const float2*)hx, (const float2*)hy, ntiles);
    hipLaunchKernelGGL(k_rlast, dim3(512 * nq), dim3(256), 0, stream, F, fc_w, part, m);
    hipLaunchKernelGGL(k_fc,    dim3(m * 10), dim3(64), 0, stream, part, fc_b, out, b0, m);
  }
}